// Round 7
// baseline (1058.026 us; speedup 1.0000x reference)
//
#include <hip/hip_runtime.h>
#include <hip/hip_bf16.h>

#define NN 50000
#define NE 800000
#define DN 160
#define DE 32
#define NP 50176              /* NN padded to 196*256 */

typedef __attribute__((ext_vector_type(8))) short bf16x8;
typedef __attribute__((ext_vector_type(4))) float f32x4;
typedef __attribute__((ext_vector_type(2))) float f32x2;
typedef __attribute__((ext_vector_type(4))) unsigned short u16x4;

#define R2 0.81649658092772603f   /* sqrt(2/3): W2 rel scale */
#define R4 1.41421356237309515f   /* sqrt(2):   W4 rel scale */
#define SC (1.0f/32.0f)           /* global scale folded into weights */

__device__ __forceinline__ unsigned short bfu16(float f) {
    union { __hip_bfloat16 h; unsigned short s; } u;
    u.h = __float2bfloat16(f);
    return u.s;
}
__device__ __forceinline__ short bfbits(float f) { return (short)bfu16(f); }
__device__ __forceinline__ float bf2f(unsigned short s) {
    union { float f; unsigned int u; } u;
    u.u = ((unsigned int)s) << 16;
    return u.f;
}

// ---- zero T + histogram counters ----
__global__ __launch_bounds__(256) void zero_kernel(float* __restrict__ T,
                                                   int* __restrict__ cnt) {
    int i = blockIdx.x * 256 + threadIdx.x;
    if (i < NN * DN) T[i] = 0.0f;
    if (i < NP) cnt[i] = 0;
}

__global__ __launch_bounds__(256) void hist_kernel(const int* __restrict__ eidx,
                                                   int* __restrict__ cnt) {
    int e = blockIdx.x * 256 + threadIdx.x;
    if (e < NE) atomicAdd(&cnt[eidx[e]], 1);
}

// block-level exclusive scan (256 elems) -> cursor, block sums -> bsum
__global__ __launch_bounds__(256) void scan1_kernel(const int* __restrict__ cnt,
                                                    int* __restrict__ cursor,
                                                    int* __restrict__ bsum) {
    __shared__ int s[256];
    const int t = threadIdx.x;
    const int i = blockIdx.x * 256 + t;
    const int v = cnt[i];
    s[t] = v; __syncthreads();
    for (int off = 1; off < 256; off <<= 1) {
        int u = (t >= off) ? s[t - off] : 0;
        __syncthreads(); s[t] += u; __syncthreads();
    }
    cursor[i] = s[t] - v;
    if (t == 255) bsum[blockIdx.x] = s[255];
}

__global__ __launch_bounds__(256) void scan2_kernel(int* __restrict__ bsum) {
    __shared__ int s[256];
    const int t = threadIdx.x;
    const int v = (t < 196) ? bsum[t] : 0;
    s[t] = v; __syncthreads();
    for (int off = 1; off < 256; off <<= 1) {
        int u = (t >= off) ? s[t - off] : 0;
        __syncthreads(); s[t] += u; __syncthreads();
    }
    if (t < 196) bsum[t] = s[t] - v;
}

__global__ __launch_bounds__(256) void scan3_kernel(int* __restrict__ cursor,
                                                    const int* __restrict__ bsum) {
    int i = blockIdx.x * 256 + threadIdx.x;
    cursor[i] += bsum[blockIdx.x];
}

__global__ __launch_bounds__(256) void scatter_kernel(const int* __restrict__ eidx,
                                                      int* __restrict__ cursor,
                                                      int* __restrict__ sorted) {
    int e = blockIdx.x * 256 + threadIdx.x;
    if (e < NE) {
        int pos = atomicAdd(&cursor[eidx[e]], 1);
        sorted[pos] = e;
    }
}

// ---- edge-TP weights: bf16, pre-scaled, MFMA 16x16x32 B-frag layout ----
__global__ __launch_bounds__(256) void wprep_edge_kernel(
    const float* __restrict__ W1, const float* __restrict__ W2,
    const float* __restrict__ W3, const float* __restrict__ W4,
    unsigned short* __restrict__ Wbf)
{
    int id = blockIdx.x * 256 + threadIdx.x;   // 73728 total
    float w;
    if (id < 49152) {
        int j = id & 7, l = (id >> 3) & 63, t = (id >> 9) % 24, n16 = id / 12288;
        int c = n16 * 16 + (l & 15);
        int k = 32 * t + 8 * (l >> 4) + j;
        if (k < 512) { int a = k >> 3, b = k & 7; w = W1[(a*8+b)*64 + c] * SC; }
        else { int k2 = k - 512; int a = k2 >> 3, b = k2 & 7; w = W2[(a*8+b)*64 + c] * (R2*SC); }
    } else {
        int id2 = id - 49152;
        int j = id2 & 7, l = (id2 >> 3) & 63, t = (id2 >> 9) % 24, n16 = id2 / 12288;
        int c = n16 * 16 + (l & 15);
        int k = 32 * t + 8 * (l >> 4) + j;
        if (k < 512) { int a = k >> 3, b = k & 7; w = W3[(a*8+b)*32 + c] * SC; }
        else { int k2 = k - 512; int a = k2 >> 3, b = k2 & 7; w = W4[(a*8+b)*32 + c] * (R4*SC); }
    }
    Wbf[id] = bfu16(w);
}

// ---- Wc = Wm @ Wu_bot (fp32), bc = bm @ Wu_bot ----
__global__ __launch_bounds__(256) void wcomp_kernel(
    const float* __restrict__ Wm, const float* __restrict__ bm,
    const float* __restrict__ Wu, float* __restrict__ Wc, float* __restrict__ bc)
{
    int id = blockIdx.x * 256 + threadIdx.x;
    if (id < 160 * 160) {
        int k = id / 160, c = id % 160;
        float s = 0.0f;
        for (int h = 0; h < 160; ++h) s = fmaf(Wm[k*160 + h], Wu[(160 + h)*160 + c], s);
        Wc[id] = s;
    }
    if (id < 160) {
        float s = 0.0f;
        for (int h = 0; h < 160; ++h) s = fmaf(bm[h], Wu[(160 + h)*160 + id], s);
        bc[id] = s;
    }
}

// ---- node-GEMM weights: [Wu_top(160); Wc permuted to T's i-major layout] ----
__global__ __launch_bounds__(256) void wprep_node_kernel(
    const float* __restrict__ Wu, const float* __restrict__ Wc,
    unsigned short* __restrict__ Wn)
{
    int id = blockIdx.x * 256 + threadIdx.x;   // 51200 total
    if (id >= 51200) return;
    int j = id & 7, l = (id >> 3) & 63, tn = id >> 9;  // tn = n16*10 + tk
    int tk = tn % 10, n16 = tn / 10;
    int c = n16 * 16 + (l & 15);
    int k = 32 * tk + 8 * (l >> 4) + j;
    float w;
    if (k < 160) {
        w = Wu[k * 160 + c];
    } else {
        int tcol = k - 160;  // T col: [0,64)=s ; 64+i*32+cc (i-major v)
        int orig = (tcol < 64) ? tcol : 64 + ((tcol - 64) & 31) * 3 + ((tcol - 64) >> 5);
        w = Wc[orig * 160 + c];
    }
    Wn[id] = bfu16(w);
}

// ---- per-edge TP via MFMA on dest-sorted edges; LDS segment-reduce;
//      plain store for interior nodes, atomicAdd only for boundary runs.
//      A-fragment products via f32x2 (v_pk_mul/fma_f32); 2-chunk epilogue
//      shrinks LDS to 38.9KB -> 4 blocks/CU. ----
__global__ __launch_bounds__(256, 4) void edge_kernel(
    const float* __restrict__ x, const int* __restrict__ eidx,
    const float* __restrict__ ea, const unsigned short* __restrict__ Wbf,
    const int* __restrict__ sorted, float* __restrict__ T)
{
    // union: stage1 (xs|xv|e = 38144 B)  vs  stage2 (accw 32*161*4 = 20608 B)
    __shared__ __align__(16) char smem[64*66*4 + 64*100*2 + 64*33*4];
    __shared__ int rowls[64];
    __shared__ int colls[64];
    __shared__ int sels[64];

    float* xsls = (float*)smem;                                    // [64][66] fp32
    unsigned short* xvls = (unsigned short*)(smem + 64*66*4);      // [64][100] bf16
    float* els = (float*)(smem + 64*66*4 + 64*100*2);              // [64][33] fp32

    const int t = threadIdx.x;
    const int base = blockIdx.x * 64;

    if (t < 64) {
        const int se = sorted[base + t];
        sels[t] = se;
        rowls[t] = eidx[se];
        colls[t] = eidx[NE + se];
    }
    __syncthreads();

    for (int j = t; j < 64 * 40; j += 256) {
        int m = j / 40, q = j - m * 40;
        const float4 v = *reinterpret_cast<const float4*>(x + (size_t)colls[m] * DN + q * 4);
        if (q < 16) {
            xsls[m*66 + q*4+0] = v.x; xsls[m*66 + q*4+1] = v.y;
            xsls[m*66 + q*4+2] = v.z; xsls[m*66 + q*4+3] = v.w;
        } else {
            u16x4 p; p[0] = bfu16(v.x); p[1] = bfu16(v.y); p[2] = bfu16(v.z); p[3] = bfu16(v.w);
            *reinterpret_cast<u16x4*>(&xvls[m*100 + q*4 - 64]) = p;
        }
    }
    for (int j = t; j < 64 * 8; j += 256) {
        int m = j >> 3, q = j & 7;
        const float4 v = *reinterpret_cast<const float4*>(ea + (size_t)sels[m] * DE + q * 4);
        els[m*33 + q*4+0] = v.x; els[m*33 + q*4+1] = v.y;
        els[m*33 + q*4+2] = v.z; els[m*33 + q*4+3] = v.w;
    }
    __syncthreads();

    const int lane = t & 63;
    const int wv = t >> 6;        // 0..3
    const int r = lane & 15;      // A row / B col / C col
    const int g = lane >> 4;      // k-group
    const int er = wv * 16 + r;   // edge owning this lane's A row

    // pre-paired edge attrs: es2[p] = {es[2p], es[2p+1]};
    // ev2[i][p] = {ev[2p][i], ev[2p+1][i]}  (32 VGPRs total, same as scalar)
    f32x2 es2[4], ev2[3][4];
    #pragma unroll
    for (int p = 0; p < 4; ++p) {
        es2[p] = (f32x2){ els[er*33 + 2*p], els[er*33 + 2*p + 1] };
        #pragma unroll
        for (int i = 0; i < 3; ++i)
            ev2[i][p] = (f32x2){ els[er*33 + 8 + 6*p + i], els[er*33 + 8 + 6*p + 3 + i] };
    }

    f32x4 accS[4], accV[3][2];
    #pragma unroll
    for (int n = 0; n < 4; ++n) accS[n] = (f32x4){0.f, 0.f, 0.f, 0.f};
    #pragma unroll
    for (int i = 0; i < 3; ++i)
        #pragma unroll
        for (int n = 0; n < 2; ++n) accV[i][n] = (f32x4){0.f, 0.f, 0.f, 0.f};

    const unsigned short* Ws = Wbf;          // s-part
    const unsigned short* Wv = Wbf + 49152;  // v-part

    for (int tt = 0; tt < 24; ++tt) {
        bf16x8 bS[4], bV[2];
        #pragma unroll
        for (int n = 0; n < 4; ++n)
            bS[n] = *reinterpret_cast<const bf16x8*>(Ws + ((size_t)(n * 24 + tt) * 64 + lane) * 8);
        #pragma unroll
        for (int n = 0; n < 2; ++n)
            bV[n] = *reinterpret_cast<const bf16x8*>(Wv + ((size_t)(n * 24 + tt) * 64 + lane) * 8);

        bf16x8 aS, aV0, aV1, aV2;
        if (tt < 16) {
            const int a = 4 * tt + g;
            const float xa = xsls[er*66 + a];
            const f32x2 xa2 = (f32x2){xa, xa};
            #pragma unroll
            for (int p = 0; p < 4; ++p) {
                const f32x2 vS = xa2 * es2[p];
                const f32x2 v0 = xa2 * ev2[0][p];
                const f32x2 v1 = xa2 * ev2[1][p];
                const f32x2 v2 = xa2 * ev2[2][p];
                aS[2*p]  = bfbits(vS[0]); aS[2*p+1]  = bfbits(vS[1]);
                aV0[2*p] = bfbits(v0[0]); aV0[2*p+1] = bfbits(v0[1]);
                aV1[2*p] = bfbits(v1[0]); aV1[2*p+1] = bfbits(v1[1]);
                aV2[2*p] = bfbits(v2[0]); aV2[2*p+1] = bfbits(v2[1]);
            }
        } else {
            const int a = 4 * (tt - 16) + g;
            const float x0 = bf2f(xvls[er*100 + a*3 + 0]);
            const float x1 = bf2f(xvls[er*100 + a*3 + 1]);
            const float x2 = bf2f(xvls[er*100 + a*3 + 2]);
            const f32x2 x02 = (f32x2){x0, x0};
            const f32x2 x12 = (f32x2){x1, x1};
            const f32x2 x22 = (f32x2){x2, x2};
            #pragma unroll
            for (int p = 0; p < 4; ++p) {
                f32x2 d = x02 * ev2[0][p];
                d += x12 * ev2[1][p];
                d += x22 * ev2[2][p];
                const f32x2 q0 = x02 * es2[p];
                const f32x2 q1 = x12 * es2[p];
                const f32x2 q2 = x22 * es2[p];
                aS[2*p]  = bfbits(d[0]);  aS[2*p+1]  = bfbits(d[1]);
                aV0[2*p] = bfbits(q0[0]); aV0[2*p+1] = bfbits(q0[1]);
                aV1[2*p] = bfbits(q1[0]); aV1[2*p+1] = bfbits(q1[1]);
                aV2[2*p] = bfbits(q2[0]); aV2[2*p+1] = bfbits(q2[1]);
            }
        }

        #pragma unroll
        for (int n = 0; n < 4; ++n)
            accS[n] = __builtin_amdgcn_mfma_f32_16x16x32_bf16(aS, bS[n], accS[n], 0, 0, 0);
        #pragma unroll
        for (int n = 0; n < 2; ++n) {
            accV[0][n] = __builtin_amdgcn_mfma_f32_16x16x32_bf16(aV0, bV[n], accV[0][n], 0, 0, 0);
            accV[1][n] = __builtin_amdgcn_mfma_f32_16x16x32_bf16(aV1, bV[n], accV[1][n], 0, 0, 0);
            accV[2][n] = __builtin_amdgcn_mfma_f32_16x16x32_bf16(aV2, bV[n], accV[2][n], 0, 0, 0);
        }
    }

    __syncthreads();   // done with staging; reuse smem for acc (2 chunks of 32)
    float* accw = (float*)smem;  // [32][161]

    #pragma unroll
    for (int half = 0; half < 2; ++half) {
        if ((wv >> 1) == half) {
            const int lbase = (wv & 1) * 16 + g * 4;
            #pragma unroll
            for (int reg = 0; reg < 4; ++reg) {
                const int lrow = lbase + reg;
                #pragma unroll
                for (int n = 0; n < 4; ++n)
                    accw[lrow*161 + n*16 + r] = accS[n][reg];
                #pragma unroll
                for (int i = 0; i < 3; ++i)
                    #pragma unroll
                    for (int n = 0; n < 2; ++n)
                        accw[lrow*161 + 64 + i*32 + n*16 + r] = accV[i][n][reg];  // i-major
            }
        }
        __syncthreads();

        if (t < DN) {
            const int col = t;
            const int ebase = half * 32;
            float s = 0.0f;
            int rstart = 0;
            for (int e = 0; e < 32; ++e) {
                s += accw[e*161 + col];
                const int ge = ebase + e;
                if (e == 31 || rowls[ge] != rowls[ge + 1]) {
                    float* dst = T + (size_t)rowls[ge] * DN + col;
                    if (rstart == 0 || e == 31) atomicAdd(dst, s);  // chunk-boundary run
                    else *dst = s;                                   // interior: exclusive
                    s = 0.0f; rstart = e + 1;
                }
            }
        }
        __syncthreads();
    }
}

// ---- node update: out = x + [bf16(x), bf16(T)] @ Wn + bu + deg*bc ----
__global__ __launch_bounds__(256) void node_kernel(
    const float* __restrict__ x, float* __restrict__ T,
    const int* __restrict__ cnt, const unsigned short* __restrict__ Wn,
    const float* __restrict__ bu, const float* __restrict__ bc)
{
    __shared__ __align__(16) unsigned short A[64][328];  // 160 x | 160 T (bf16)
    const int t = threadIdx.x;
    const int nb = blockIdx.x * 64;

    for (int j = t; j < 64 * 80; j += 256) {
        int m = j / 80, q = j - m * 80;
        int row = nb + m; if (row >= NN) row = NN - 1;
        const float* src = (q < 40) ? (x + (size_t)row * DN + q * 4)
                                    : (T + (size_t)row * DN + (q - 40) * 4);
        const float4 v = *reinterpret_cast<const float4*>(src);
        int o = (q < 40) ? q * 4 : 160 + (q - 40) * 4;
        u16x4 p; p[0] = bfu16(v.x); p[1] = bfu16(v.y); p[2] = bfu16(v.z); p[3] = bfu16(v.w);
        *reinterpret_cast<u16x4*>(&A[m][o]) = p;
    }
    __syncthreads();

    const int lane = t & 63;
    const int wv = t >> 6;
    const int r = lane & 15, g = lane >> 4;
    const int er = wv * 16 + r;

    f32x4 acc[10];
    #pragma unroll
    for (int n = 0; n < 10; ++n) acc[n] = (f32x4){0.f, 0.f, 0.f, 0.f};

    for (int tk = 0; tk < 10; ++tk) {
        const bf16x8 a = *reinterpret_cast<const bf16x8*>(&A[er][32 * tk + 8 * g]);
        #pragma unroll
        for (int n = 0; n < 10; ++n) {
            const bf16x8 b = *reinterpret_cast<const bf16x8*>(Wn + ((size_t)(n * 10 + tk) * 64 + lane) * 8);
            acc[n] = __builtin_amdgcn_mfma_f32_16x16x32_bf16(a, b, acc[n], 0, 0, 0);
        }
    }

    #pragma unroll
    for (int reg = 0; reg < 4; ++reg) {
        const int nrow = nb + wv * 16 + g * 4 + reg;
        if (nrow < NN) {
            const float dg = (float)cnt[nrow];
            #pragma unroll
            for (int n = 0; n < 10; ++n) {
                const int c = n * 16 + r;
                T[(size_t)nrow * DN + c] =
                    acc[n][reg] + x[(size_t)nrow * DN + c] + bu[c] + dg * bc[c];
            }
        }
    }
}

extern "C" void kernel_launch(void* const* d_in, const int* in_sizes, int n_in,
                              void* d_out, int out_size, void* d_ws, size_t ws_size,
                              hipStream_t stream) {
    const float* xf   = (const float*)d_in[0];
    const int*   eidx = (const int*)d_in[1];
    const float* ea   = (const float*)d_in[2];
    const float* W1 = (const float*)d_in[4];
    const float* W2 = (const float*)d_in[5];
    const float* W3 = (const float*)d_in[6];
    const float* W4 = (const float*)d_in[7];
    const float* Wm = (const float*)d_in[8];
    const float* bm = (const float*)d_in[9];
    const float* Wu = (const float*)d_in[10];
    const float* bu = (const float*)d_in[11];

    float* out = (float*)d_out;   // doubles as tp-accumulator T

    char* ws = (char*)d_ws;
    int*            cnt    = (int*)ws;                              // 256 KB slot
    int*            cursor = (int*)(ws + (256 << 10));              // 256 KB slot
    int*            sorted = (int*)(ws + (512 << 10));              // 3.2 MB
    int*            bsum   = (int*)(ws + (4096 << 10));             // 1 KB
    unsigned short* Wbf    = (unsigned short*)(ws + (4112 << 10));  // 144 KB
    float*          Wc     = (float*)(ws + (4288 << 10));           // 100 KB
    float*          bc     = (float*)(ws + (4416 << 10));           // 640 B
    unsigned short* Wn     = (unsigned short*)(ws + (4432 << 10));  // 100 KB

    wcomp_kernel<<<100, 256, 0, stream>>>(Wm, bm, Wu, Wc, bc);
    wprep_node_kernel<<<200, 256, 0, stream>>>(Wu, Wc, Wn);
    wprep_edge_kernel<<<288, 256, 0, stream>>>(W1, W2, W3, W4, Wbf);
    zero_kernel<<<(NN * DN + 255) / 256, 256, 0, stream>>>(out, cnt);
    hist_kernel<<<NE / 256, 256, 0, stream>>>(eidx, cnt);
    scan1_kernel<<<NP / 256, 256, 0, stream>>>(cnt, cursor, bsum);
    scan2_kernel<<<1, 256, 0, stream>>>(bsum);
    scan3_kernel<<<NP / 256, 256, 0, stream>>>(cursor, bsum);
    scatter_kernel<<<NE / 256, 256, 0, stream>>>(eidx, cursor, sorted);
    edge_kernel<<<NE / 64, 256, 0, stream>>>(xf, eidx, ea, Wbf, sorted, out);
    node_kernel<<<(NN + 63) / 64, 256, 0, stream>>>(xf, out, cnt, Wn, bu, bc);
}

// Round 8
// 527.922 us; speedup vs baseline: 2.0041x; 2.0041x over previous
//
#include <hip/hip_runtime.h>
#include <hip/hip_bf16.h>

#define NN 50000
#define NE 800000
#define DN 160
#define DE 32
#define NP 50176              /* NN padded to 196*256 */

typedef __attribute__((ext_vector_type(8))) short bf16x8;
typedef __attribute__((ext_vector_type(4))) float f32x4;
typedef __attribute__((ext_vector_type(2))) float f32x2;
typedef __attribute__((ext_vector_type(4))) unsigned short u16x4;

#define R2 0.81649658092772603f   /* sqrt(2/3): W2 rel scale */
#define R4 1.41421356237309515f   /* sqrt(2):   W4 rel scale */
#define SC (1.0f/32.0f)           /* global scale folded into weights */

__device__ __forceinline__ unsigned short bfu16(float f) {
    union { __hip_bfloat16 h; unsigned short s; } u;
    u.h = __float2bfloat16(f);
    return u.s;
}
__device__ __forceinline__ short bfbits(float f) { return (short)bfu16(f); }
__device__ __forceinline__ float bf2f(unsigned short s) {
    union { float f; unsigned int u; } u;
    u.u = ((unsigned int)s) << 16;
    return u.f;
}

// ---- zero T + histogram counters ----
__global__ __launch_bounds__(256) void zero_kernel(float* __restrict__ T,
                                                   int* __restrict__ cnt) {
    int i = blockIdx.x * 256 + threadIdx.x;
    if (i < NN * DN) T[i] = 0.0f;
    if (i < NP) cnt[i] = 0;
}

__global__ __launch_bounds__(256) void hist_kernel(const int* __restrict__ eidx,
                                                   int* __restrict__ cnt) {
    int e = blockIdx.x * 256 + threadIdx.x;
    if (e < NE) atomicAdd(&cnt[eidx[e]], 1);
}

// block-level exclusive scan (256 elems) -> cursor, block sums -> bsum
__global__ __launch_bounds__(256) void scan1_kernel(const int* __restrict__ cnt,
                                                    int* __restrict__ cursor,
                                                    int* __restrict__ bsum) {
    __shared__ int s[256];
    const int t = threadIdx.x;
    const int i = blockIdx.x * 256 + t;
    const int v = cnt[i];
    s[t] = v; __syncthreads();
    for (int off = 1; off < 256; off <<= 1) {
        int u = (t >= off) ? s[t - off] : 0;
        __syncthreads(); s[t] += u; __syncthreads();
    }
    cursor[i] = s[t] - v;
    if (t == 255) bsum[blockIdx.x] = s[255];
}

__global__ __launch_bounds__(256) void scan2_kernel(int* __restrict__ bsum) {
    __shared__ int s[256];
    const int t = threadIdx.x;
    const int v = (t < 196) ? bsum[t] : 0;
    s[t] = v; __syncthreads();
    for (int off = 1; off < 256; off <<= 1) {
        int u = (t >= off) ? s[t - off] : 0;
        __syncthreads(); s[t] += u; __syncthreads();
    }
    if (t < 196) bsum[t] = s[t] - v;
}

__global__ __launch_bounds__(256) void scan3_kernel(int* __restrict__ cursor,
                                                    const int* __restrict__ bsum) {
    int i = blockIdx.x * 256 + threadIdx.x;
    cursor[i] += bsum[blockIdx.x];
}

__global__ __launch_bounds__(256) void scatter_kernel(const int* __restrict__ eidx,
                                                      int* __restrict__ cursor,
                                                      int* __restrict__ sorted) {
    int e = blockIdx.x * 256 + threadIdx.x;
    if (e < NE) {
        int pos = atomicAdd(&cursor[eidx[e]], 1);
        sorted[pos] = e;
    }
}

// ---- edge-TP weights: bf16, pre-scaled, MFMA 16x16x32 B-frag layout ----
__global__ __launch_bounds__(256) void wprep_edge_kernel(
    const float* __restrict__ W1, const float* __restrict__ W2,
    const float* __restrict__ W3, const float* __restrict__ W4,
    unsigned short* __restrict__ Wbf)
{
    int id = blockIdx.x * 256 + threadIdx.x;   // 73728 total
    float w;
    if (id < 49152) {
        int j = id & 7, l = (id >> 3) & 63, t = (id >> 9) % 24, n16 = id / 12288;
        int c = n16 * 16 + (l & 15);
        int k = 32 * t + 8 * (l >> 4) + j;
        if (k < 512) { int a = k >> 3, b = k & 7; w = W1[(a*8+b)*64 + c] * SC; }
        else { int k2 = k - 512; int a = k2 >> 3, b = k2 & 7; w = W2[(a*8+b)*64 + c] * (R2*SC); }
    } else {
        int id2 = id - 49152;
        int j = id2 & 7, l = (id2 >> 3) & 63, t = (id2 >> 9) % 24, n16 = id2 / 12288;
        int c = n16 * 16 + (l & 15);
        int k = 32 * t + 8 * (l >> 4) + j;
        if (k < 512) { int a = k >> 3, b = k & 7; w = W3[(a*8+b)*32 + c] * SC; }
        else { int k2 = k - 512; int a = k2 >> 3, b = k2 & 7; w = W4[(a*8+b)*32 + c] * (R4*SC); }
    }
    Wbf[id] = bfu16(w);
}

// ---- Wc = Wm @ Wu_bot (fp32), bc = bm @ Wu_bot ----
__global__ __launch_bounds__(256) void wcomp_kernel(
    const float* __restrict__ Wm, const float* __restrict__ bm,
    const float* __restrict__ Wu, float* __restrict__ Wc, float* __restrict__ bc)
{
    int id = blockIdx.x * 256 + threadIdx.x;
    if (id < 160 * 160) {
        int k = id / 160, c = id % 160;
        float s = 0.0f;
        for (int h = 0; h < 160; ++h) s = fmaf(Wm[k*160 + h], Wu[(160 + h)*160 + c], s);
        Wc[id] = s;
    }
    if (id < 160) {
        float s = 0.0f;
        for (int h = 0; h < 160; ++h) s = fmaf(bm[h], Wu[(160 + h)*160 + id], s);
        bc[id] = s;
    }
}

// ---- node-GEMM weights: [Wu_top(160); Wc permuted to T's i-major layout] ----
__global__ __launch_bounds__(256) void wprep_node_kernel(
    const float* __restrict__ Wu, const float* __restrict__ Wc,
    unsigned short* __restrict__ Wn)
{
    int id = blockIdx.x * 256 + threadIdx.x;   // 51200 total
    if (id >= 51200) return;
    int j = id & 7, l = (id >> 3) & 63, tn = id >> 9;  // tn = n16*10 + tk
    int tk = tn % 10, n16 = tn / 10;
    int c = n16 * 16 + (l & 15);
    int k = 32 * tk + 8 * (l >> 4) + j;
    float w;
    if (k < 160) {
        w = Wu[k * 160 + c];
    } else {
        int tcol = k - 160;  // T col: [0,64)=s ; 64+i*32+cc (i-major v)
        int orig = (tcol < 64) ? tcol : 64 + ((tcol - 64) & 31) * 3 + ((tcol - 64) >> 5);
        w = Wc[orig * 160 + c];
    }
    Wn[id] = bfu16(w);
}

// ---- per-edge TP via MFMA on dest-sorted edges; LDS segment-reduce;
//      plain store for interior nodes, atomicAdd only for boundary runs.
//      f32x2 packed product formation; 2-chunk epilogue -> LDS 38.9KB
//      -> 4 blocks/CU at VGPR<=128 (NO vgpr cap: R7's (256,4) caused spills) ----
__global__ __launch_bounds__(256, 3) void edge_kernel(
    const float* __restrict__ x, const int* __restrict__ eidx,
    const float* __restrict__ ea, const unsigned short* __restrict__ Wbf,
    const int* __restrict__ sorted, float* __restrict__ T)
{
    // union: stage1 (xs|xv|e = 38144 B)  vs  stage2 (accw 32*161*4 = 20608 B)
    __shared__ __align__(16) char smem[64*66*4 + 64*100*2 + 64*33*4];
    __shared__ int rowls[64];
    __shared__ int colls[64];
    __shared__ int sels[64];

    float* xsls = (float*)smem;                                    // [64][66] fp32
    unsigned short* xvls = (unsigned short*)(smem + 64*66*4);      // [64][100] bf16
    float* els = (float*)(smem + 64*66*4 + 64*100*2);              // [64][33] fp32

    const int t = threadIdx.x;
    const int base = blockIdx.x * 64;

    if (t < 64) {
        const int se = sorted[base + t];
        sels[t] = se;
        rowls[t] = eidx[se];
        colls[t] = eidx[NE + se];
    }
    __syncthreads();

    for (int j = t; j < 64 * 40; j += 256) {
        int m = j / 40, q = j - m * 40;
        const float4 v = *reinterpret_cast<const float4*>(x + (size_t)colls[m] * DN + q * 4);
        if (q < 16) {
            xsls[m*66 + q*4+0] = v.x; xsls[m*66 + q*4+1] = v.y;
            xsls[m*66 + q*4+2] = v.z; xsls[m*66 + q*4+3] = v.w;
        } else {
            u16x4 p; p[0] = bfu16(v.x); p[1] = bfu16(v.y); p[2] = bfu16(v.z); p[3] = bfu16(v.w);
            *reinterpret_cast<u16x4*>(&xvls[m*100 + q*4 - 64]) = p;
        }
    }
    for (int j = t; j < 64 * 8; j += 256) {
        int m = j >> 3, q = j & 7;
        const float4 v = *reinterpret_cast<const float4*>(ea + (size_t)sels[m] * DE + q * 4);
        els[m*33 + q*4+0] = v.x; els[m*33 + q*4+1] = v.y;
        els[m*33 + q*4+2] = v.z; els[m*33 + q*4+3] = v.w;
    }
    __syncthreads();

    const int lane = t & 63;
    const int wv = t >> 6;        // 0..3
    const int r = lane & 15;      // A row / B col / C col
    const int g = lane >> 4;      // k-group
    const int er = wv * 16 + r;   // edge owning this lane's A row

    // pre-paired edge attrs: es2[p] = {es[2p], es[2p+1]};
    // ev2[i][p] = {ev[2p][i], ev[2p+1][i]}
    f32x2 es2[4], ev2[3][4];
    #pragma unroll
    for (int p = 0; p < 4; ++p) {
        es2[p] = (f32x2){ els[er*33 + 2*p], els[er*33 + 2*p + 1] };
        #pragma unroll
        for (int i = 0; i < 3; ++i)
            ev2[i][p] = (f32x2){ els[er*33 + 8 + 6*p + i], els[er*33 + 8 + 6*p + 3 + i] };
    }

    f32x4 accS[4], accV[3][2];
    #pragma unroll
    for (int n = 0; n < 4; ++n) accS[n] = (f32x4){0.f, 0.f, 0.f, 0.f};
    #pragma unroll
    for (int i = 0; i < 3; ++i)
        #pragma unroll
        for (int n = 0; n < 2; ++n) accV[i][n] = (f32x4){0.f, 0.f, 0.f, 0.f};

    const unsigned short* Ws = Wbf;          // s-part
    const unsigned short* Wv = Wbf + 49152;  // v-part

    for (int tt = 0; tt < 24; ++tt) {
        bf16x8 bS[4], bV[2];
        #pragma unroll
        for (int n = 0; n < 4; ++n)
            bS[n] = *reinterpret_cast<const bf16x8*>(Ws + ((size_t)(n * 24 + tt) * 64 + lane) * 8);
        #pragma unroll
        for (int n = 0; n < 2; ++n)
            bV[n] = *reinterpret_cast<const bf16x8*>(Wv + ((size_t)(n * 24 + tt) * 64 + lane) * 8);

        bf16x8 aS, aV0, aV1, aV2;
        if (tt < 16) {
            const int a = 4 * tt + g;
            const float xa = xsls[er*66 + a];
            const f32x2 xa2 = (f32x2){xa, xa};
            #pragma unroll
            for (int p = 0; p < 4; ++p) {
                const f32x2 vS = xa2 * es2[p];
                const f32x2 v0 = xa2 * ev2[0][p];
                const f32x2 v1 = xa2 * ev2[1][p];
                const f32x2 v2 = xa2 * ev2[2][p];
                aS[2*p]  = bfbits(vS[0]); aS[2*p+1]  = bfbits(vS[1]);
                aV0[2*p] = bfbits(v0[0]); aV0[2*p+1] = bfbits(v0[1]);
                aV1[2*p] = bfbits(v1[0]); aV1[2*p+1] = bfbits(v1[1]);
                aV2[2*p] = bfbits(v2[0]); aV2[2*p+1] = bfbits(v2[1]);
            }
        } else {
            const int a = 4 * (tt - 16) + g;
            const float x0 = bf2f(xvls[er*100 + a*3 + 0]);
            const float x1 = bf2f(xvls[er*100 + a*3 + 1]);
            const float x2 = bf2f(xvls[er*100 + a*3 + 2]);
            const f32x2 x02 = (f32x2){x0, x0};
            const f32x2 x12 = (f32x2){x1, x1};
            const f32x2 x22 = (f32x2){x2, x2};
            #pragma unroll
            for (int p = 0; p < 4; ++p) {
                f32x2 d = x02 * ev2[0][p];
                d += x12 * ev2[1][p];
                d += x22 * ev2[2][p];
                const f32x2 q0 = x02 * es2[p];
                const f32x2 q1 = x12 * es2[p];
                const f32x2 q2 = x22 * es2[p];
                aS[2*p]  = bfbits(d[0]);  aS[2*p+1]  = bfbits(d[1]);
                aV0[2*p] = bfbits(q0[0]); aV0[2*p+1] = bfbits(q0[1]);
                aV1[2*p] = bfbits(q1[0]); aV1[2*p+1] = bfbits(q1[1]);
                aV2[2*p] = bfbits(q2[0]); aV2[2*p+1] = bfbits(q2[1]);
            }
        }

        #pragma unroll
        for (int n = 0; n < 4; ++n)
            accS[n] = __builtin_amdgcn_mfma_f32_16x16x32_bf16(aS, bS[n], accS[n], 0, 0, 0);
        #pragma unroll
        for (int n = 0; n < 2; ++n) {
            accV[0][n] = __builtin_amdgcn_mfma_f32_16x16x32_bf16(aV0, bV[n], accV[0][n], 0, 0, 0);
            accV[1][n] = __builtin_amdgcn_mfma_f32_16x16x32_bf16(aV1, bV[n], accV[1][n], 0, 0, 0);
            accV[2][n] = __builtin_amdgcn_mfma_f32_16x16x32_bf16(aV2, bV[n], accV[2][n], 0, 0, 0);
        }
    }

    __syncthreads();   // done with staging; reuse smem for acc (2 chunks of 32)
    float* accw = (float*)smem;  // [32][161]

    #pragma unroll
    for (int half = 0; half < 2; ++half) {
        if ((wv >> 1) == half) {
            const int lbase = (wv & 1) * 16 + g * 4;
            #pragma unroll
            for (int reg = 0; reg < 4; ++reg) {
                const int lrow = lbase + reg;
                #pragma unroll
                for (int n = 0; n < 4; ++n)
                    accw[lrow*161 + n*16 + r] = accS[n][reg];
                #pragma unroll
                for (int i = 0; i < 3; ++i)
                    #pragma unroll
                    for (int n = 0; n < 2; ++n)
                        accw[lrow*161 + 64 + i*32 + n*16 + r] = accV[i][n][reg];  // i-major
            }
        }
        __syncthreads();

        if (t < DN) {
            const int col = t;
            const int ebase = half * 32;
            float s = 0.0f;
            int rstart = 0;
            for (int e = 0; e < 32; ++e) {
                s += accw[e*161 + col];
                const int ge = ebase + e;
                if (e == 31 || rowls[ge] != rowls[ge + 1]) {
                    float* dst = T + (size_t)rowls[ge] * DN + col;
                    if (rstart == 0 || e == 31) atomicAdd(dst, s);  // chunk-boundary run
                    else *dst = s;                                   // interior: exclusive
                    s = 0.0f; rstart = e + 1;
                }
            }
        }
        __syncthreads();
    }
}

// ---- node update: out = x + [bf16(x), bf16(T)] @ Wn + bu + deg*bc ----
__global__ __launch_bounds__(256) void node_kernel(
    const float* __restrict__ x, float* __restrict__ T,
    const int* __restrict__ cnt, const unsigned short* __restrict__ Wn,
    const float* __restrict__ bu, const float* __restrict__ bc)
{
    __shared__ __align__(16) unsigned short A[64][328];  // 160 x | 160 T (bf16)
    const int t = threadIdx.x;
    const int nb = blockIdx.x * 64;

    for (int j = t; j < 64 * 80; j += 256) {
        int m = j / 80, q = j - m * 80;
        int row = nb + m; if (row >= NN) row = NN - 1;
        const float* src = (q < 40) ? (x + (size_t)row * DN + q * 4)
                                    : (T + (size_t)row * DN + (q - 40) * 4);
        const float4 v = *reinterpret_cast<const float4*>(src);
        int o = (q < 40) ? q * 4 : 160 + (q - 40) * 4;
        u16x4 p; p[0] = bfu16(v.x); p[1] = bfu16(v.y); p[2] = bfu16(v.z); p[3] = bfu16(v.w);
        *reinterpret_cast<u16x4*>(&A[m][o]) = p;
    }
    __syncthreads();

    const int lane = t & 63;
    const int wv = t >> 6;
    const int r = lane & 15, g = lane >> 4;
    const int er = wv * 16 + r;

    f32x4 acc[10];
    #pragma unroll
    for (int n = 0; n < 10; ++n) acc[n] = (f32x4){0.f, 0.f, 0.f, 0.f};

    for (int tk = 0; tk < 10; ++tk) {
        const bf16x8 a = *reinterpret_cast<const bf16x8*>(&A[er][32 * tk + 8 * g]);
        #pragma unroll
        for (int n = 0; n < 10; ++n) {
            const bf16x8 b = *reinterpret_cast<const bf16x8*>(Wn + ((size_t)(n * 10 + tk) * 64 + lane) * 8);
            acc[n] = __builtin_amdgcn_mfma_f32_16x16x32_bf16(a, b, acc[n], 0, 0, 0);
        }
    }

    #pragma unroll
    for (int reg = 0; reg < 4; ++reg) {
        const int nrow = nb + wv * 16 + g * 4 + reg;
        if (nrow < NN) {
            const float dg = (float)cnt[nrow];
            #pragma unroll
            for (int n = 0; n < 10; ++n) {
                const int c = n * 16 + r;
                T[(size_t)nrow * DN + c] =
                    acc[n][reg] + x[(size_t)nrow * DN + c] + bu[c] + dg * bc[c];
            }
        }
    }
}

extern "C" void kernel_launch(void* const* d_in, const int* in_sizes, int n_in,
                              void* d_out, int out_size, void* d_ws, size_t ws_size,
                              hipStream_t stream) {
    const float* xf   = (const float*)d_in[0];
    const int*   eidx = (const int*)d_in[1];
    const float* ea   = (const float*)d_in[2];
    const float* W1 = (const float*)d_in[4];
    const float* W2 = (const float*)d_in[5];
    const float* W3 = (const float*)d_in[6];
    const float* W4 = (const float*)d_in[7];
    const float* Wm = (const float*)d_in[8];
    const float* bm = (const float*)d_in[9];
    const float* Wu = (const float*)d_in[10];
    const float* bu = (const float*)d_in[11];

    float* out = (float*)d_out;   // doubles as tp-accumulator T

    char* ws = (char*)d_ws;
    int*            cnt    = (int*)ws;                              // 256 KB slot
    int*            cursor = (int*)(ws + (256 << 10));              // 256 KB slot
    int*            sorted = (int*)(ws + (512 << 10));              // 3.2 MB
    int*            bsum   = (int*)(ws + (4096 << 10));             // 1 KB
    unsigned short* Wbf    = (unsigned short*)(ws + (4112 << 10));  // 144 KB
    float*          Wc     = (float*)(ws + (4288 << 10));           // 100 KB
    float*          bc     = (float*)(ws + (4416 << 10));           // 640 B
    unsigned short* Wn     = (unsigned short*)(ws + (4432 << 10));  // 100 KB

    wcomp_kernel<<<100, 256, 0, stream>>>(Wm, bm, Wu, Wc, bc);
    wprep_node_kernel<<<200, 256, 0, stream>>>(Wu, Wc, Wn);
    wprep_edge_kernel<<<288, 256, 0, stream>>>(W1, W2, W3, W4, Wbf);
    zero_kernel<<<(NN * DN + 255) / 256, 256, 0, stream>>>(out, cnt);
    hist_kernel<<<NE / 256, 256, 0, stream>>>(eidx, cnt);
    scan1_kernel<<<NP / 256, 256, 0, stream>>>(cnt, cursor, bsum);
    scan2_kernel<<<1, 256, 0, stream>>>(bsum);
    scan3_kernel<<<NP / 256, 256, 0, stream>>>(cursor, bsum);
    scatter_kernel<<<NE / 256, 256, 0, stream>>>(eidx, cursor, sorted);
    edge_kernel<<<NE / 64, 256, 0, stream>>>(xf, eidx, ea, Wbf, sorted, out);
    node_kernel<<<(NN + 63) / 64, 256, 0, stream>>>(xf, out, cnt, Wn, bu, bc);
}

// Round 9
// 473.136 us; speedup vs baseline: 2.2362x; 1.1158x over previous
//
#include <hip/hip_runtime.h>
#include <hip/hip_bf16.h>

#define NN 50000
#define NE 800000
#define DN 160
#define DE 32
#define NP 50176              /* NN padded to 196*256 */

typedef __attribute__((ext_vector_type(8))) short bf16x8;
typedef __attribute__((ext_vector_type(4))) float f32x4;
typedef __attribute__((ext_vector_type(2))) float f32x2;
typedef __attribute__((ext_vector_type(4))) unsigned short u16x4;
typedef __attribute__((ext_vector_type(8))) unsigned short u16x8;

#define R2 0.81649658092772603f   /* sqrt(2/3): W2 rel scale */
#define R4 1.41421356237309515f   /* sqrt(2):   W4 rel scale */
#define SC (1.0f/32.0f)           /* global scale folded into weights */

__device__ __forceinline__ unsigned short bfu16(float f) {
    union { __hip_bfloat16 h; unsigned short s; } u;
    u.h = __float2bfloat16(f);
    return u.s;
}
__device__ __forceinline__ short bfbits(float f) { return (short)bfu16(f); }
__device__ __forceinline__ float bf2f(unsigned short s) {
    union { float f; unsigned int u; } u;
    u.u = ((unsigned int)s) << 16;
    return u.f;
}

// ---- x -> bf16 copy (one-time) ----
__global__ __launch_bounds__(256) void xprep_kernel(const float* __restrict__ x,
                                                    unsigned short* __restrict__ xb) {
    int i = blockIdx.x * 256 + threadIdx.x;   // float4 index
    if (i < NN * DN / 4) {
        const float4 v = reinterpret_cast<const float4*>(x)[i];
        u16x4 p; p[0] = bfu16(v.x); p[1] = bfu16(v.y); p[2] = bfu16(v.z); p[3] = bfu16(v.w);
        reinterpret_cast<u16x4*>(xb)[i] = p;
    }
}

// ---- zero T + histogram counters ----
__global__ __launch_bounds__(256) void zero_kernel(float* __restrict__ T,
                                                   int* __restrict__ cnt) {
    int i = blockIdx.x * 256 + threadIdx.x;
    if (i < NN * DN) T[i] = 0.0f;
    if (i < NP) cnt[i] = 0;
}

__global__ __launch_bounds__(256) void hist_kernel(const int* __restrict__ eidx,
                                                   int* __restrict__ cnt) {
    int e = blockIdx.x * 256 + threadIdx.x;
    if (e < NE) atomicAdd(&cnt[eidx[e]], 1);
}

__global__ __launch_bounds__(256) void scan1_kernel(const int* __restrict__ cnt,
                                                    int* __restrict__ cursor,
                                                    int* __restrict__ bsum) {
    __shared__ int s[256];
    const int t = threadIdx.x;
    const int i = blockIdx.x * 256 + t;
    const int v = cnt[i];
    s[t] = v; __syncthreads();
    for (int off = 1; off < 256; off <<= 1) {
        int u = (t >= off) ? s[t - off] : 0;
        __syncthreads(); s[t] += u; __syncthreads();
    }
    cursor[i] = s[t] - v;
    if (t == 255) bsum[blockIdx.x] = s[255];
}

__global__ __launch_bounds__(256) void scan2_kernel(int* __restrict__ bsum) {
    __shared__ int s[256];
    const int t = threadIdx.x;
    const int v = (t < 196) ? bsum[t] : 0;
    s[t] = v; __syncthreads();
    for (int off = 1; off < 256; off <<= 1) {
        int u = (t >= off) ? s[t - off] : 0;
        __syncthreads(); s[t] += u; __syncthreads();
    }
    if (t < 196) bsum[t] = s[t] - v;
}

__global__ __launch_bounds__(256) void scan3_kernel(int* __restrict__ cursor,
                                                    const int* __restrict__ bsum) {
    int i = blockIdx.x * 256 + threadIdx.x;
    cursor[i] += bsum[blockIdx.x];
}

__global__ __launch_bounds__(256) void scatter_kernel(const int* __restrict__ eidx,
                                                      int* __restrict__ cursor,
                                                      int* __restrict__ sorted) {
    int e = blockIdx.x * 256 + threadIdx.x;
    if (e < NE) {
        int pos = atomicAdd(&cursor[eidx[e]], 1);
        sorted[pos] = e;
    }
}

// ---- edge-TP weights: bf16, pre-scaled, MFMA B-frag layout, tt-CONSECUTIVE:
//      elem id = ((tt*6 + s)*64 + lane)*8 + j ; s<4: s-tile (cols s*16+..,[W1;W2]);
//      s>=4: v-tile (cols (s-4)*16+.., [W3;W4]); k = 32*tt + 8*(lane>>4) + j ----
__global__ __launch_bounds__(256) void wprep_edge_kernel(
    const float* __restrict__ W1, const float* __restrict__ W2,
    const float* __restrict__ W3, const float* __restrict__ W4,
    unsigned short* __restrict__ Wbf)
{
    int id = blockIdx.x * 256 + threadIdx.x;   // 73728 total
    if (id >= 73728) return;
    int j = id & 7, l = (id >> 3) & 63, st = id >> 9;  // st = tt*6+s
    int tt = st / 6, s = st % 6;
    int k = 32 * tt + 8 * (l >> 4) + j;
    float w;
    if (s < 4) {
        int c = s * 16 + (l & 15);
        if (k < 512) { int a = k >> 3, b = k & 7; w = W1[(a*8+b)*64 + c] * SC; }
        else { int k2 = k - 512; int a = k2 >> 3, b = k2 & 7; w = W2[(a*8+b)*64 + c] * (R2*SC); }
    } else {
        int c = (s - 4) * 16 + (l & 15);
        if (k < 512) { int a = k >> 3, b = k & 7; w = W3[(a*8+b)*32 + c] * SC; }
        else { int k2 = k - 512; int a = k2 >> 3, b = k2 & 7; w = W4[(a*8+b)*32 + c] * (R4*SC); }
    }
    Wbf[id] = bfu16(w);
}

// ---- Wc = Wm @ Wu_bot (fp32), bc = bm @ Wu_bot ----
__global__ __launch_bounds__(256) void wcomp_kernel(
    const float* __restrict__ Wm, const float* __restrict__ bm,
    const float* __restrict__ Wu, float* __restrict__ Wc, float* __restrict__ bc)
{
    int id = blockIdx.x * 256 + threadIdx.x;
    if (id < 160 * 160) {
        int k = id / 160, c = id % 160;
        float s = 0.0f;
        for (int h = 0; h < 160; ++h) s = fmaf(Wm[k*160 + h], Wu[(160 + h)*160 + c], s);
        Wc[id] = s;
    }
    if (id < 160) {
        float s = 0.0f;
        for (int h = 0; h < 160; ++h) s = fmaf(bm[h], Wu[(160 + h)*160 + id], s);
        bc[id] = s;
    }
}

// ---- node-GEMM weights: [Wu_top(160); Wc permuted to T's i-major layout] ----
__global__ __launch_bounds__(256) void wprep_node_kernel(
    const float* __restrict__ Wu, const float* __restrict__ Wc,
    unsigned short* __restrict__ Wn)
{
    int id = blockIdx.x * 256 + threadIdx.x;   // 51200 total
    if (id >= 51200) return;
    int j = id & 7, l = (id >> 3) & 63, tn = id >> 9;  // tn = n16*10 + tk
    int tk = tn % 10, n16 = tn / 10;
    int c = n16 * 16 + (l & 15);
    int k = 32 * tk + 8 * (l >> 4) + j;
    float w;
    if (k < 160) {
        w = Wu[k * 160 + c];
    } else {
        int tcol = k - 160;  // T col: [0,64)=s ; 64+i*32+cc (i-major v)
        int orig = (tcol < 64) ? tcol : 64 + ((tcol - 64) & 31) * 3 + ((tcol - 64) >> 5);
        w = Wc[orig * 160 + c];
    }
    Wn[id] = bfu16(w);
}

// ---- per-edge TP via MFMA on dest-sorted edges; LDS segment-reduce;
//      merged bf16 x-tile in LDS (31KB); tt-consecutive weight loads ----
template<int UXB>
__global__ __launch_bounds__(256, 3) void edge_kernel(
    const float* __restrict__ x, const unsigned short* __restrict__ xb,
    const int* __restrict__ eidx, const float* __restrict__ ea,
    const unsigned short* __restrict__ Wbf,
    const int* __restrict__ sorted, float* __restrict__ T)
{
    // stage1: xls[64][168] bf16 (21504 B) + els[64][33] f32 (8448 B) = 29952 B
    // stage2: accw[32][161] f32 (20608 B) overlays
    __shared__ __align__(16) char smem[64*168*2 + 64*33*4];
    __shared__ int rowls[64];
    __shared__ int colls[64];
    __shared__ int sels[64];

    unsigned short* xls = (unsigned short*)smem;         // [64][168] bf16
    float* els = (float*)(smem + 64*168*2);              // [64][33] fp32

    const int t = threadIdx.x;
    const int base = blockIdx.x * 64;

    if (t < 64) {
        const int se = sorted[base + t];
        sels[t] = se;
        rowls[t] = eidx[se];
        colls[t] = eidx[NE + se];
    }
    __syncthreads();

    if (UXB) {
        // gather bf16 rows: 64 edges x 20 u16x8 (16B each)
        for (int j = t; j < 64 * 20; j += 256) {
            int m = j / 20, q = j - m * 20;
            const u16x8 v = *reinterpret_cast<const u16x8*>(xb + (size_t)colls[m] * DN + q * 8);
            *reinterpret_cast<u16x8*>(&xls[m*168 + q*8]) = v;
        }
    } else {
        for (int j = t; j < 64 * 40; j += 256) {
            int m = j / 40, q = j - m * 40;
            const float4 v = *reinterpret_cast<const float4*>(x + (size_t)colls[m] * DN + q * 4);
            u16x4 p; p[0] = bfu16(v.x); p[1] = bfu16(v.y); p[2] = bfu16(v.z); p[3] = bfu16(v.w);
            *reinterpret_cast<u16x4*>(&xls[m*168 + q*4]) = p;
        }
    }
    for (int j = t; j < 64 * 8; j += 256) {
        int m = j >> 3, q = j & 7;
        const float4 v = *reinterpret_cast<const float4*>(ea + (size_t)sels[m] * DE + q * 4);
        els[m*33 + q*4+0] = v.x; els[m*33 + q*4+1] = v.y;
        els[m*33 + q*4+2] = v.z; els[m*33 + q*4+3] = v.w;
    }
    __syncthreads();

    const int lane = t & 63;
    const int wv = t >> 6;        // 0..3
    const int r = lane & 15;      // A row / B col / C col
    const int g = lane >> 4;      // k-group
    const int er = wv * 16 + r;   // edge owning this lane's A row

    // pre-paired edge attrs
    f32x2 es2[4], ev2[3][4];
    #pragma unroll
    for (int p = 0; p < 4; ++p) {
        es2[p] = (f32x2){ els[er*33 + 2*p], els[er*33 + 2*p + 1] };
        #pragma unroll
        for (int i = 0; i < 3; ++i)
            ev2[i][p] = (f32x2){ els[er*33 + 8 + 6*p + i], els[er*33 + 8 + 6*p + 3 + i] };
    }

    f32x4 accS[4], accV[3][2];
    #pragma unroll
    for (int n = 0; n < 4; ++n) accS[n] = (f32x4){0.f, 0.f, 0.f, 0.f};
    #pragma unroll
    for (int i = 0; i < 3; ++i)
        #pragma unroll
        for (int n = 0; n < 2; ++n) accV[i][n] = (f32x4){0.f, 0.f, 0.f, 0.f};

    // two pointer streams: wpA offsets 0..3072B, wpB(+4096B) offsets 0,1024B
    const unsigned short* wpA = Wbf + (size_t)lane * 8;
    const unsigned short* wpB = Wbf + 2048 + (size_t)lane * 8;

    for (int tt = 0; tt < 24; ++tt) {
        bf16x8 bS[4], bV[2];
        bS[0] = *reinterpret_cast<const bf16x8*>(wpA);
        bS[1] = *reinterpret_cast<const bf16x8*>(wpA + 512);
        bS[2] = *reinterpret_cast<const bf16x8*>(wpA + 1024);
        bS[3] = *reinterpret_cast<const bf16x8*>(wpA + 1536);
        bV[0] = *reinterpret_cast<const bf16x8*>(wpB);
        bV[1] = *reinterpret_cast<const bf16x8*>(wpB + 512);
        wpA += 3072; wpB += 3072;

        bf16x8 aS, aV0, aV1, aV2;
        if (tt < 16) {
            const int a = 4 * tt + g;
            const float xa = bf2f(xls[er*168 + a]);
            const f32x2 xa2 = (f32x2){xa, xa};
            #pragma unroll
            for (int p = 0; p < 4; ++p) {
                const f32x2 vS = xa2 * es2[p];
                const f32x2 v0 = xa2 * ev2[0][p];
                const f32x2 v1 = xa2 * ev2[1][p];
                const f32x2 v2 = xa2 * ev2[2][p];
                aS[2*p]  = bfbits(vS[0]); aS[2*p+1]  = bfbits(vS[1]);
                aV0[2*p] = bfbits(v0[0]); aV0[2*p+1] = bfbits(v0[1]);
                aV1[2*p] = bfbits(v1[0]); aV1[2*p+1] = bfbits(v1[1]);
                aV2[2*p] = bfbits(v2[0]); aV2[2*p+1] = bfbits(v2[1]);
            }
        } else {
            const int a = 4 * (tt - 16) + g;
            const float x0 = bf2f(xls[er*168 + 64 + a*3 + 0]);
            const float x1 = bf2f(xls[er*168 + 64 + a*3 + 1]);
            const float x2 = bf2f(xls[er*168 + 64 + a*3 + 2]);
            const f32x2 x02 = (f32x2){x0, x0};
            const f32x2 x12 = (f32x2){x1, x1};
            const f32x2 x22 = (f32x2){x2, x2};
            #pragma unroll
            for (int p = 0; p < 4; ++p) {
                f32x2 d = x02 * ev2[0][p];
                d += x12 * ev2[1][p];
                d += x22 * ev2[2][p];
                const f32x2 q0 = x02 * es2[p];
                const f32x2 q1 = x12 * es2[p];
                const f32x2 q2 = x22 * es2[p];
                aS[2*p]  = bfbits(d[0]);  aS[2*p+1]  = bfbits(d[1]);
                aV0[2*p] = bfbits(q0[0]); aV0[2*p+1] = bfbits(q0[1]);
                aV1[2*p] = bfbits(q1[0]); aV1[2*p+1] = bfbits(q1[1]);
                aV2[2*p] = bfbits(q2[0]); aV2[2*p+1] = bfbits(q2[1]);
            }
        }

        #pragma unroll
        for (int n = 0; n < 4; ++n)
            accS[n] = __builtin_amdgcn_mfma_f32_16x16x32_bf16(aS, bS[n], accS[n], 0, 0, 0);
        #pragma unroll
        for (int n = 0; n < 2; ++n) {
            accV[0][n] = __builtin_amdgcn_mfma_f32_16x16x32_bf16(aV0, bV[n], accV[0][n], 0, 0, 0);
            accV[1][n] = __builtin_amdgcn_mfma_f32_16x16x32_bf16(aV1, bV[n], accV[1][n], 0, 0, 0);
            accV[2][n] = __builtin_amdgcn_mfma_f32_16x16x32_bf16(aV2, bV[n], accV[2][n], 0, 0, 0);
        }
    }

    __syncthreads();   // done with staging; reuse smem for acc (2 chunks of 32)
    float* accw = (float*)smem;  // [32][161]

    #pragma unroll
    for (int half = 0; half < 2; ++half) {
        if ((wv >> 1) == half) {
            const int lbase = (wv & 1) * 16 + g * 4;
            #pragma unroll
            for (int reg = 0; reg < 4; ++reg) {
                const int lrow = lbase + reg;
                #pragma unroll
                for (int n = 0; n < 4; ++n)
                    accw[lrow*161 + n*16 + r] = accS[n][reg];
                #pragma unroll
                for (int i = 0; i < 3; ++i)
                    #pragma unroll
                    for (int n = 0; n < 2; ++n)
                        accw[lrow*161 + 64 + i*32 + n*16 + r] = accV[i][n][reg];  // i-major
            }
        }
        __syncthreads();

        if (t < DN) {
            const int col = t;
            const int ebase = half * 32;
            float s = 0.0f;
            int rstart = 0;
            for (int e = 0; e < 32; ++e) {
                s += accw[e*161 + col];
                const int ge = ebase + e;
                if (e == 31 || rowls[ge] != rowls[ge + 1]) {
                    float* dst = T + (size_t)rowls[ge] * DN + col;
                    if (rstart == 0 || e == 31) atomicAdd(dst, s);  // chunk-boundary run
                    else *dst = s;                                   // interior: exclusive
                    s = 0.0f; rstart = e + 1;
                }
            }
        }
        __syncthreads();
    }
}

// ---- node update: out = x + [bf16(x), bf16(T)] @ Wn + bu + deg*bc ----
template<int UXB>
__global__ __launch_bounds__(256) void node_kernel(
    const float* __restrict__ x, const unsigned short* __restrict__ xb,
    float* __restrict__ T, const int* __restrict__ cnt,
    const unsigned short* __restrict__ Wn,
    const float* __restrict__ bu, const float* __restrict__ bc)
{
    __shared__ __align__(16) unsigned short A[64][328];  // 160 x | 160 T (bf16)
    const int t = threadIdx.x;
    const int nb = blockIdx.x * 64;

    if (UXB) {
        for (int j = t; j < 64 * 20; j += 256) {   // x-part straight bf16 copy
            int m = j / 20, q = j - m * 20;
            int row = nb + m; if (row >= NN) row = NN - 1;
            const u16x8 v = *reinterpret_cast<const u16x8*>(xb + (size_t)row * DN + q * 8);
            *reinterpret_cast<u16x8*>(&A[m][q*8]) = v;
        }
        for (int j = t; j < 64 * 40; j += 256) {   // T-part with cvt
            int m = j / 40, q = j - m * 40;
            int row = nb + m; if (row >= NN) row = NN - 1;
            const float4 v = *reinterpret_cast<const float4*>(T + (size_t)row * DN + q * 4);
            u16x4 p; p[0] = bfu16(v.x); p[1] = bfu16(v.y); p[2] = bfu16(v.z); p[3] = bfu16(v.w);
            *reinterpret_cast<u16x4*>(&A[m][160 + q*4]) = p;
        }
    } else {
        for (int j = t; j < 64 * 80; j += 256) {
            int m = j / 80, q = j - m * 80;
            int row = nb + m; if (row >= NN) row = NN - 1;
            const float* src = (q < 40) ? (x + (size_t)row * DN + q * 4)
                                        : (T + (size_t)row * DN + (q - 40) * 4);
            const float4 v = *reinterpret_cast<const float4*>(src);
            int o = (q < 40) ? q * 4 : 160 + (q - 40) * 4;
            u16x4 p; p[0] = bfu16(v.x); p[1] = bfu16(v.y); p[2] = bfu16(v.z); p[3] = bfu16(v.w);
            *reinterpret_cast<u16x4*>(&A[m][o]) = p;
        }
    }
    __syncthreads();

    const int lane = t & 63;
    const int wv = t >> 6;
    const int r = lane & 15, g = lane >> 4;
    const int er = wv * 16 + r;

    f32x4 acc[10];
    #pragma unroll
    for (int n = 0; n < 10; ++n) acc[n] = (f32x4){0.f, 0.f, 0.f, 0.f};

    for (int tk = 0; tk < 10; ++tk) {
        const bf16x8 a = *reinterpret_cast<const bf16x8*>(&A[er][32 * tk + 8 * g]);
        #pragma unroll
        for (int n = 0; n < 10; ++n) {
            const bf16x8 b = *reinterpret_cast<const bf16x8*>(Wn + ((size_t)(n * 10 + tk) * 64 + lane) * 8);
            acc[n] = __builtin_amdgcn_mfma_f32_16x16x32_bf16(a, b, acc[n], 0, 0, 0);
        }
    }

    #pragma unroll
    for (int reg = 0; reg < 4; ++reg) {
        const int nrow = nb + wv * 16 + g * 4 + reg;
        if (nrow < NN) {
            const float dg = (float)cnt[nrow];
            #pragma unroll
            for (int n = 0; n < 10; ++n) {
                const int c = n * 16 + r;
                T[(size_t)nrow * DN + c] =
                    acc[n][reg] + x[(size_t)nrow * DN + c] + bu[c] + dg * bc[c];
            }
        }
    }
}

extern "C" void kernel_launch(void* const* d_in, const int* in_sizes, int n_in,
                              void* d_out, int out_size, void* d_ws, size_t ws_size,
                              hipStream_t stream) {
    const float* xf   = (const float*)d_in[0];
    const int*   eidx = (const int*)d_in[1];
    const float* ea   = (const float*)d_in[2];
    const float* W1 = (const float*)d_in[4];
    const float* W2 = (const float*)d_in[5];
    const float* W3 = (const float*)d_in[6];
    const float* W4 = (const float*)d_in[7];
    const float* Wm = (const float*)d_in[8];
    const float* bm = (const float*)d_in[9];
    const float* Wu = (const float*)d_in[10];
    const float* bu = (const float*)d_in[11];

    float* out = (float*)d_out;   // doubles as tp-accumulator T

    char* ws = (char*)d_ws;
    int*            cnt    = (int*)ws;                              // 200 KB
    int*            cursor = (int*)(ws + (256 << 10));              // 200 KB
    int*            sorted = (int*)(ws + (512 << 10));              // 3.2 MB
    int*            bsum   = (int*)(ws + (3968 << 10));             // 1 KB
    unsigned short* Wbf    = (unsigned short*)(ws + (4096 << 10));  // 144 KB
    float*          Wc     = (float*)(ws + (4352 << 10));           // 100 KB
    float*          bc     = (float*)(ws + (4480 << 10));           // 640 B
    unsigned short* Wn     = (unsigned short*)(ws + (4608 << 10));  // 100 KB
    unsigned short* xb     = (unsigned short*)(ws + (4864 << 10));  // 16 MB bf16 x

    const bool uxb = ws_size >= ((size_t)(4864 + 16000) << 10);

    wcomp_kernel<<<100, 256, 0, stream>>>(Wm, bm, Wu, Wc, bc);
    wprep_node_kernel<<<200, 256, 0, stream>>>(Wu, Wc, Wn);
    wprep_edge_kernel<<<288, 256, 0, stream>>>(W1, W2, W3, W4, Wbf);
    if (uxb) xprep_kernel<<<(NN * DN / 4 + 255) / 256, 256, 0, stream>>>(xf, xb);
    zero_kernel<<<(NN * DN + 255) / 256, 256, 0, stream>>>(out, cnt);
    hist_kernel<<<NE / 256, 256, 0, stream>>>(eidx, cnt);
    scan1_kernel<<<NP / 256, 256, 0, stream>>>(cnt, cursor, bsum);
    scan2_kernel<<<1, 256, 0, stream>>>(bsum);
    scan3_kernel<<<NP / 256, 256, 0, stream>>>(cursor, bsum);
    scatter_kernel<<<NE / 256, 256, 0, stream>>>(eidx, cursor, sorted);
    if (uxb) {
        edge_kernel<1><<<NE / 64, 256, 0, stream>>>(xf, xb, eidx, ea, Wbf, sorted, out);
        node_kernel<1><<<(NN + 63) / 64, 256, 0, stream>>>(xf, xb, out, cnt, Wn, bu, bc);
    } else {
        edge_kernel<0><<<NE / 64, 256, 0, stream>>>(xf, xb, eidx, ea, Wbf, sorted, out);
        node_kernel<0><<<(NN + 63) / 64, 256, 0, stream>>>(xf, xb, out, cnt, Wn, bu, bc);
    }
}